// Round 2
// baseline (243.902 us; speedup 1.0000x reference)
//
#include <hip/hip_runtime.h>
#include <cstdint>
#include <cstddef>

// Problem constants (from reference setup_inputs)
#define C_ 4
#define B_ 128
#define G_ 2048
#define S_ 32
#define L_ 3
#define NSTEP_ 3
#define GAMMA_ 0.01f
// exp((x)*100) == exp2((x)*144.2695...), gamma*ln(a) = gamma*ln2*log2(a)
#define INVG_LOG2E_ 144.26950408889634f
#define GAMMA_LN2_ 0.0069314718055994530942f

// Slot layout: slot s occupies uint indices [s*128, s*128+128) = 512 B,
// with 8 atomic "banks" at 64 B stride (slots[s*128 + k*16]).
__device__ __forceinline__ float slot_max(const uint32_t* slots, int slot) {
  float m = 0.0f;
#pragma unroll
  for (int k = 0; k < 8; ++k)
    m = fmaxf(m, __uint_as_float(slots[slot * 128 + k * 16]));
  return m;
}

// ---------------------------------------------------------------------------
// k_initT: xT[g,b] = x[b,g]  (1 MB transpose; no clause broadcast — step-0
// gather/elem read xT with clause-stride 0)
// ---------------------------------------------------------------------------
__global__ __launch_bounds__(256) void k_initT(const float* __restrict__ x,
                                               float* __restrict__ xT) {
  __shared__ float tile[32][33];
  const int g0 = blockIdx.x * 32, b0 = blockIdx.y * 32;
  const int tx = threadIdx.x;
  for (int i = threadIdx.y; i < 32; i += 8)
    tile[i][tx] = x[(size_t)(b0 + i) * G_ + g0 + tx];  // tile[b-b0][g-g0]
  __syncthreads();
  for (int j = threadIdx.y; j < 32; j += 8)
    xT[(size_t)(g0 + j) * B_ + b0 + tx] = tile[tx][j];
}

// ---------------------------------------------------------------------------
// k_gather: ONE WAVE per (c,g); each lane owns 2 b-columns (float2 loads:
// one 512 B wave-request per row instead of two 256 B). Row indices are
// wave-uniform (readfirstlane -> SGPR base; loads are saddr + lane*8).
// Online logsumexp (running max, rescaled acc) avoids body[32] storage.
// scale^3 of the previous step's lazy normalization folded into exponent.
// XCD-bijective swizzle keeps each XCD's L2 on one clause slice.
// ---------------------------------------------------------------------------
__global__ __launch_bounds__(64, 4) void k_gather(
    const float* __restrict__ Abase, size_t cstride,
    const int* __restrict__ Idx, float* __restrict__ Lout,
    uint32_t* slots, int prev_slot, int out_slot) {
  const int lane = threadIdx.x;
  const int bid = blockIdx.x;
  // bijective XCD swizzle (8192 % 8 == 0)
  const int cg = ((bid & 7) << 10) | (bid >> 3);
  const int c = cg >> 11;  // / G_

  const float mprev = slot_max(slots, prev_slot);
  const float scale = (mprev > 1.0f) ? (1.0f / mprev) : 1.0f;
  const float s3 = scale * scale * scale;
  const float K = s3 * INVG_LOG2E_;

  const int ibase = cg * (S_ * L_);
  const float* Ac = Abase + (size_t)c * cstride + 2 * lane;

  float M0 = -1.0f, M1 = -1.0f;  // body in [0,1]
  float acc0 = 0.0f, acc1 = 0.0f;
#pragma unroll
  for (int s = 0; s < S_; ++s) {
    // uniform address -> scalar loads; readfirstlane pins rows to SGPRs
    const int r0 = __builtin_amdgcn_readfirstlane(Idx[ibase + 3 * s + 0]);
    const int r1 = __builtin_amdgcn_readfirstlane(Idx[ibase + 3 * s + 1]);
    const int r2 = __builtin_amdgcn_readfirstlane(Idx[ibase + 3 * s + 2]);
    const float2 v0 = *(const float2*)(Ac + (size_t)r0 * B_);
    const float2 v1 = *(const float2*)(Ac + (size_t)r1 * B_);
    const float2 v2 = *(const float2*)(Ac + (size_t)r2 * B_);
    const float b0 = v0.x * v1.x * v2.x;  // raw product; s3 folded into K
    const float b1 = v0.y * v1.y * v2.y;
    const float n0 = fmaxf(M0, b0);
    acc0 = acc0 * exp2f((M0 - n0) * K) + exp2f((b0 - n0) * K);
    M0 = n0;
    const float n1 = fmaxf(M1, b1);
    acc1 = acc1 * exp2f((M1 - n1) * K) + exp2f((b1 - n1) * K);
    M1 = n1;
  }
  const float lse0 = M0 * s3 + GAMMA_LN2_ * log2f(acc0);
  const float lse1 = M1 * s3 + GAMMA_LN2_ * log2f(acc1);
  *(float2*)(Lout + (size_t)cg * B_ + 2 * lane) = make_float2(lse0, lse1);

  // wave max -> one banked global atomic per block
  float t = fmaxf(lse0, lse1);
#pragma unroll
  for (int off = 32; off >= 1; off >>= 1) t = fmaxf(t, __shfl_xor(t, off));
  if (lane == 0)
    atomicMax(slots + out_slot * 128 + (bid & 7) * 16, __float_as_uint(t));
}

// ---------------------------------------------------------------------------
// k_elem: R = Rin*sprev; ce = lse1*s1; A = 2-elem softor(R, ce).
// Rin/rstride lets step 0 read the 1 MB xT (clause-stride 0).
// Exactly one float4 per thread: 1024 blocks x 256 threads x 4 = C*G*B.
// ---------------------------------------------------------------------------
__global__ __launch_bounds__(256) void k_elem(
    const float* __restrict__ Rin, size_t rstride, float* __restrict__ A,
    const float* __restrict__ Lin, uint32_t* slots, int prev_slot,
    int m1_slot, int out_slot) {
  __shared__ float wmax[4];
  const float mprev = slot_max(slots, prev_slot);
  const float sprev = (mprev > 1.0f) ? (1.0f / mprev) : 1.0f;
  const float m1 = slot_max(slots, m1_slot);
  const float s1 = (m1 > 1.0f) ? (1.0f / m1) : 1.0f;

  const int e = (blockIdx.x * 256 + threadIdx.x) * 4;
  const int c = e >> 18;               // / (G_*B_)
  const int rem = e & (G_ * B_ - 1);   // within clause slice
  const float4 Rv = *reinterpret_cast<const float4*>(Rin + (size_t)c * rstride + rem);
  const float4 Lv = *reinterpret_cast<const float4*>(Lin + e);

  float r[4] = {Rv.x, Rv.y, Rv.z, Rv.w};
  float l[4] = {Lv.x, Lv.y, Lv.z, Lv.w};
  float o[4];
  float tmax = 0.0f;
#pragma unroll
  for (int k = 0; k < 4; ++k) {
    const float R = r[k] * sprev;
    const float ce = l[k] * s1;
    const float M = fmaxf(R, ce);
    const float mn = fminf(R, ce);
    const float lse2 =
        M + GAMMA_LN2_ * log2f(1.0f + exp2f((mn - M) * INVG_LOG2E_));
    o[k] = lse2;
    tmax = fmaxf(tmax, lse2);
  }
  *reinterpret_cast<float4*>(A + e) = make_float4(o[0], o[1], o[2], o[3]);

  float t = tmax;
#pragma unroll
  for (int off = 32; off >= 1; off >>= 1) t = fmaxf(t, __shfl_xor(t, off));
  if ((threadIdx.x & 63) == 0) wmax[threadIdx.x >> 6] = t;
  __syncthreads();
  if (threadIdx.x == 0) {
    const float bm = fmaxf(fmaxf(wmax[0], wmax[1]), fmaxf(wmax[2], wmax[3]));
    atomicMax(slots + out_slot * 128 + (blockIdx.x & 7) * 16,
              __float_as_uint(bm));
  }
}

// ---------------------------------------------------------------------------
// k_out: out[c,b,g] = A[c,g,b] * final_scale  (LDS-tiled transpose back)
// ---------------------------------------------------------------------------
__global__ __launch_bounds__(256) void k_out(const float* __restrict__ A,
                                             float* __restrict__ out,
                                             const uint32_t* __restrict__ slots,
                                             int mslot) {
  __shared__ float tile[32][33];
  const float mfin = slot_max(slots, mslot);
  const float sc = (mfin > 1.0f) ? (1.0f / mfin) : 1.0f;
  const int g0 = blockIdx.x * 32, b0 = blockIdx.y * 32, c = blockIdx.z;
  const int tx = threadIdx.x;
  for (int j = threadIdx.y; j < 32; j += 8)
    tile[j][tx] = A[((size_t)c * G_ + g0 + j) * B_ + b0 + tx];  // tile[g][b]
  __syncthreads();
  for (int i = threadIdx.y; i < 32; i += 8)
    out[((size_t)c * B_ + b0 + i) * G_ + g0 + tx] = tile[tx][i] * sc;
}

extern "C" void kernel_launch(void* const* d_in, const int* in_sizes, int n_in,
                              void* d_out, int out_size, void* d_ws,
                              size_t ws_size, hipStream_t stream) {
  const float* x = (const float*)d_in[0];  // [B,G]
  const int* Idx = (const int*)d_in[1];    // [C,G,S,L]
  float* out = (float*)d_out;              // [C,B,G]

  char* ws = (char*)d_ws;
  uint32_t* slots = (uint32_t*)ws;  // 7 slots x 512 B (8 banks x 64 B each)
  float* A = (float*)(ws + 4096);                                   // 4 MB
  float* Lb = (float*)(ws + 4096 + (size_t)C_ * G_ * B_ * 4);       // 4 MB
  float* xT = (float*)(ws + 4096 + (size_t)C_ * G_ * B_ * 8);       // 1 MB

  hipMemsetAsync(slots, 0, 4096, stream);

  k_initT<<<dim3(G_ / 32, B_ / 32), dim3(32, 8), 0, stream>>>(x, xT);

  const size_t CS = (size_t)G_ * B_;
  for (int step = 0; step < NSTEP_; ++step) {
    const int prev = 2 * step;  // m2 of previous step (all-zero -> scale 1)
    const int m1s = 2 * step + 1;
    const int m2s = 2 * step + 2;
    const float* Rsrc = (step == 0) ? xT : A;
    const size_t rs = (step == 0) ? 0 : CS;
    k_gather<<<C_ * G_, 64, 0, stream>>>(Rsrc, rs, Idx, Lb, slots, prev, m1s);
    k_elem<<<(C_ * G_ * B_) / (256 * 4), 256, 0, stream>>>(Rsrc, rs, A, Lb,
                                                           slots, prev, m1s,
                                                           m2s);
  }

  k_out<<<dim3(G_ / 32, B_ / 32, C_), dim3(32, 8), 0, stream>>>(A, out, slots,
                                                                2 * NSTEP_);
}

// Round 3
// 169.335 us; speedup vs baseline: 1.4403x; 1.4403x over previous
//
#include <hip/hip_runtime.h>
#include <cstdint>
#include <cstddef>

// Problem constants (from reference setup_inputs)
#define C_ 4
#define B_ 128
#define G_ 2048
#define S_ 32
#define L_ 3
#define NSTEP_ 3
#define GAMMA_ 0.01f
// exp((x)*100) == exp2((x)*144.2695...), gamma*ln(a) = gamma*ln2*log2(a)
#define INVG_LOG2E_ 144.26950408889634f
#define GAMMA_LN2_ 0.0069314718055994530942f

// Slot layout: slot s occupies uint indices [s*128, s*128+128) = 512 B,
// with 8 atomic "banks" at 64 B stride (slots[s*128 + k*16]).
__device__ __forceinline__ float slot_max(const uint32_t* slots, int slot) {
  float m = 0.0f;
#pragma unroll
  for (int k = 0; k < 8; ++k)
    m = fmaxf(m, __uint_as_float(slots[slot * 128 + k * 16]));
  return m;
}

// ---------------------------------------------------------------------------
// k_initT: xT[g,b] = x[b,g]  (1 MB transpose; step-0 gather/elem read xT
// with clause-stride 0 — no 4x clause broadcast writes)
// ---------------------------------------------------------------------------
__global__ __launch_bounds__(256) void k_initT(const float* __restrict__ x,
                                               float* __restrict__ xT) {
  __shared__ float tile[32][33];
  const int g0 = blockIdx.x * 32, b0 = blockIdx.y * 32;
  const int tx = threadIdx.x;
  for (int i = threadIdx.y; i < 32; i += 8)
    tile[i][tx] = x[(size_t)(b0 + i) * G_ + g0 + tx];  // tile[b-b0][g-g0]
  __syncthreads();
  for (int j = threadIdx.y; j < 32; j += 8)
    xT[(size_t)(g0 + j) * B_ + b0 + tx] = tile[tx][j];
}

// ---------------------------------------------------------------------------
// k_gather: one (c,g) per block, 128 threads = b lanes, 8192 blocks.
// Explicit MLP: loads batched in chunks of 8 substitutions (24 independent
// row loads in flight, v[24]) BEFORE any use; logsumexp is online per-CHUNK
// (4 rescale points, not a 32-deep serial chain) so VGPR stays ~<=64,
// no spills, high occupancy. Indices LDS-staged (VMEM, coalesced).
// scale^3 of the previous step's lazy normalization folded into exponent K.
// XCD-bijective swizzle keeps each XCD's L2 on one clause slice.
// ---------------------------------------------------------------------------
__global__ __launch_bounds__(128) void k_gather(
    const float* __restrict__ Abase, size_t cstride,
    const int* __restrict__ Idx, float* __restrict__ Lout,
    uint32_t* slots, int prev_slot, int out_slot) {
  __shared__ int sidx[S_ * L_];
  __shared__ float wmax[2];
  const int tid = threadIdx.x;
  const int bid = blockIdx.x;
  // bijective XCD swizzle (8192 % 8 == 0)
  const int cg = ((bid & 7) << 10) | (bid >> 3);
  const int c = cg >> 11;  // / G_

  if (tid < S_ * L_) sidx[tid] = Idx[(size_t)cg * (S_ * L_) + tid];
  const float mprev = slot_max(slots, prev_slot);
  const float scale = (mprev > 1.0f) ? (1.0f / mprev) : 1.0f;
  const float s3 = scale * scale * scale;
  const float K = s3 * INVG_LOG2E_;
  __syncthreads();

  const float* Ac = Abase + (size_t)c * cstride + tid;

  float M = -1.0f;  // body products are in [0,1]
  float acc = 0.0f;
#pragma unroll
  for (int s0 = 0; s0 < S_; s0 += 8) {
    // 24 independent row loads issued back-to-back (the MLP batch)
    float v[24];
#pragma unroll
    for (int j = 0; j < 24; ++j)
      v[j] = Ac[(size_t)sidx[s0 * 3 + j] * B_];
    float b[8];
#pragma unroll
    for (int k = 0; k < 8; ++k) b[k] = v[3 * k] * v[3 * k + 1] * v[3 * k + 2];
    float cm = b[0];
#pragma unroll
    for (int k = 1; k < 8; ++k) cm = fmaxf(cm, b[k]);
    const float Mn = fmaxf(M, cm);
    acc *= exp2f((M - Mn) * K);  // one rescale per chunk
#pragma unroll
    for (int k = 0; k < 8; ++k) acc += exp2f((b[k] - Mn) * K);
    M = Mn;
  }
  const float lse = M * s3 + GAMMA_LN2_ * log2f(acc);
  Lout[(size_t)cg * B_ + tid] = lse;

  // block max: 64-lane butterfly reduce, cross-wave via LDS, 1 banked atomic
  float t = lse;
#pragma unroll
  for (int off = 32; off >= 1; off >>= 1) t = fmaxf(t, __shfl_xor(t, off));
  if ((tid & 63) == 0) wmax[tid >> 6] = t;
  __syncthreads();
  if (tid == 0)
    atomicMax(slots + out_slot * 128 + (bid & 7) * 16,
              __float_as_uint(fmaxf(wmax[0], wmax[1])));
}

// ---------------------------------------------------------------------------
// k_elem: R = Rin*sprev; ce = lse1*s1; A = 2-elem softor(R, ce).
// Rin/rstride lets step 0 read the 1 MB xT (clause-stride 0).
// Exactly one float4 per thread: 1024 blocks x 256 threads x 4 = C*G*B.
// ---------------------------------------------------------------------------
__global__ __launch_bounds__(256) void k_elem(
    const float* __restrict__ Rin, size_t rstride, float* __restrict__ A,
    const float* __restrict__ Lin, uint32_t* slots, int prev_slot,
    int m1_slot, int out_slot) {
  __shared__ float wmax[4];
  const float mprev = slot_max(slots, prev_slot);
  const float sprev = (mprev > 1.0f) ? (1.0f / mprev) : 1.0f;
  const float m1 = slot_max(slots, m1_slot);
  const float s1 = (m1 > 1.0f) ? (1.0f / m1) : 1.0f;

  const int e = (blockIdx.x * 256 + threadIdx.x) * 4;
  const int c = e >> 18;              // / (G_*B_)
  const int rem = e & (G_ * B_ - 1);  // within clause slice
  const float4 Rv =
      *reinterpret_cast<const float4*>(Rin + (size_t)c * rstride + rem);
  const float4 Lv = *reinterpret_cast<const float4*>(Lin + e);

  float r[4] = {Rv.x, Rv.y, Rv.z, Rv.w};
  float l[4] = {Lv.x, Lv.y, Lv.z, Lv.w};
  float o[4];
  float tmax = 0.0f;
#pragma unroll
  for (int k = 0; k < 4; ++k) {
    const float R = r[k] * sprev;
    const float ce = l[k] * s1;
    const float M = fmaxf(R, ce);
    const float mn = fminf(R, ce);
    const float lse2 =
        M + GAMMA_LN2_ * log2f(1.0f + exp2f((mn - M) * INVG_LOG2E_));
    o[k] = lse2;
    tmax = fmaxf(tmax, lse2);
  }
  *reinterpret_cast<float4*>(A + e) = make_float4(o[0], o[1], o[2], o[3]);

  float t = tmax;
#pragma unroll
  for (int off = 32; off >= 1; off >>= 1) t = fmaxf(t, __shfl_xor(t, off));
  if ((threadIdx.x & 63) == 0) wmax[threadIdx.x >> 6] = t;
  __syncthreads();
  if (threadIdx.x == 0) {
    const float bm = fmaxf(fmaxf(wmax[0], wmax[1]), fmaxf(wmax[2], wmax[3]));
    atomicMax(slots + out_slot * 128 + (blockIdx.x & 7) * 16,
              __float_as_uint(bm));
  }
}

// ---------------------------------------------------------------------------
// k_out: out[c,b,g] = A[c,g,b] * final_scale  (LDS-tiled transpose back)
// ---------------------------------------------------------------------------
__global__ __launch_bounds__(256) void k_out(const float* __restrict__ A,
                                             float* __restrict__ out,
                                             const uint32_t* __restrict__ slots,
                                             int mslot) {
  __shared__ float tile[32][33];
  const float mfin = slot_max(slots, mslot);
  const float sc = (mfin > 1.0f) ? (1.0f / mfin) : 1.0f;
  const int g0 = blockIdx.x * 32, b0 = blockIdx.y * 32, c = blockIdx.z;
  const int tx = threadIdx.x;
  for (int j = threadIdx.y; j < 32; j += 8)
    tile[j][tx] = A[((size_t)c * G_ + g0 + j) * B_ + b0 + tx];  // tile[g][b]
  __syncthreads();
  for (int i = threadIdx.y; i < 32; i += 8)
    out[((size_t)c * B_ + b0 + i) * G_ + g0 + tx] = tile[tx][i] * sc;
}

extern "C" void kernel_launch(void* const* d_in, const int* in_sizes, int n_in,
                              void* d_out, int out_size, void* d_ws,
                              size_t ws_size, hipStream_t stream) {
  const float* x = (const float*)d_in[0];  // [B,G]
  const int* Idx = (const int*)d_in[1];    // [C,G,S,L]
  float* out = (float*)d_out;              // [C,B,G]

  char* ws = (char*)d_ws;
  uint32_t* slots = (uint32_t*)ws;  // 7 slots x 512 B (8 banks x 64 B each)
  float* A = (float*)(ws + 4096);                               // 4 MB
  float* Lb = (float*)(ws + 4096 + (size_t)C_ * G_ * B_ * 4);   // 4 MB
  float* xT = (float*)(ws + 4096 + (size_t)C_ * G_ * B_ * 8);   // 1 MB

  hipMemsetAsync(slots, 0, 4096, stream);

  k_initT<<<dim3(G_ / 32, B_ / 32), dim3(32, 8), 0, stream>>>(x, xT);

  const size_t CS = (size_t)G_ * B_;
  for (int step = 0; step < NSTEP_; ++step) {
    const int prev = 2 * step;  // m2 of previous step (all-zero -> scale 1)
    const int m1s = 2 * step + 1;
    const int m2s = 2 * step + 2;
    const float* Rsrc = (step == 0) ? xT : A;
    const size_t rs = (step == 0) ? 0 : CS;
    k_gather<<<C_ * G_, 128, 0, stream>>>(Rsrc, rs, Idx, Lb, slots, prev, m1s);
    k_elem<<<(C_ * G_ * B_) / (256 * 4), 256, 0, stream>>>(Rsrc, rs, A, Lb,
                                                           slots, prev, m1s,
                                                           m2s);
  }

  k_out<<<dim3(G_ / 32, B_ / 32, C_), dim3(32, 8), 0, stream>>>(A, out, slots,
                                                                2 * NSTEP_);
}

// Round 5
// 154.903 us; speedup vs baseline: 1.5745x; 1.0932x over previous
//
#include <hip/hip_runtime.h>
#include <hip/hip_fp16.h>
#include <cstdint>
#include <cstddef>

// Problem constants (from reference setup_inputs)
#define C_ 4
#define B_ 128
#define G_ 2048
#define S_ 32
#define L_ 3
#define NSTEP_ 3
#define GAMMA_ 0.01f
// exp((x)*100) == exp2((x)*144.2695...), gamma*ln(a) = gamma*ln2*log2(a)
#define INVG_LOG2E_ 144.26950408889634f
#define GAMMA_LN2_ 0.0069314718055994530942f

// Slot layout: slot s = 1 KB (256 uints) with 8 atomic banks at 128 B stride
// (one L2 line each) -> 8-way spread of same-slot atomicMax traffic.
#define SLOT_U_ 256
#define BANK_U_ 32
__device__ __forceinline__ float slot_max(const uint32_t* slots, int slot) {
  float m = 0.0f;
#pragma unroll
  for (int k = 0; k < 8; ++k)
    m = fmaxf(m, __uint_as_float(slots[slot * SLOT_U_ + k * BANK_U_]));
  return m;
}

// ---------------------------------------------------------------------------
// k_initT: xT[g,b] = x[b,g] (fp32, 1 MB) and x16[g,b] (fp16 mirror, 0.5 MB).
// Step-0 gather reads x16 (clause-stride 0); step-0 elem reads xT.
// ---------------------------------------------------------------------------
__global__ __launch_bounds__(256) void k_initT(const float* __restrict__ x,
                                               float* __restrict__ xT,
                                               __half* __restrict__ x16) {
  __shared__ float tile[32][33];
  const int g0 = blockIdx.x * 32, b0 = blockIdx.y * 32;
  const int tx = threadIdx.x;
  for (int i = threadIdx.y; i < 32; i += 8)
    tile[i][tx] = x[(size_t)(b0 + i) * G_ + g0 + tx];  // tile[b-b0][g-g0]
  __syncthreads();
  for (int j = threadIdx.y; j < 32; j += 8) {
    const float v = tile[tx][j];
    xT[(size_t)(g0 + j) * B_ + b0 + tx] = v;
    x16[(size_t)(g0 + j) * B_ + b0 + tx] = __float2half_rn(v);
  }
}

// ---------------------------------------------------------------------------
// k_gather: ONE WAVE per (c,g); 64 lanes x __half2 = the whole 128-b fp16 row
// in a single 256 B request (96 requests/cg vs 192 fp32; 8192 waves vs 16384).
// Block = 128 threads = 2 waves = 2 consecutive cg. Indices LDS-staged with a
// STRIDED loop (192 ints > 128 threads — round-4's crash was the missing
// second iteration leaving sidx[128..191] uninitialized).
// Chunked online logsumexp (8 substitutions per chunk, 24 half2 loads in
// flight, one rescale per chunk) keeps VGPR ~60 -> high occupancy.
// scale^3 of the previous step's lazy normalization folded into exponent K.
// XCD-bijective swizzle keeps each XCD's L2 on one clause slice.
// ---------------------------------------------------------------------------
__global__ __launch_bounds__(128) void k_gather(
    const __half* __restrict__ A16, size_t cstride,
    const int* __restrict__ Idx, float* __restrict__ Lout,
    uint32_t* slots, int prev_slot, int out_slot) {
  __shared__ int sidx[2 * S_ * L_];
  const int tid = threadIdx.x;
  const int lane = tid & 63;
  const int w = tid >> 6;
  const int bid = blockIdx.x;
  // bijective XCD swizzle (4096 block-pairs = 8 * 512)
  const int cgp = ((bid & 7) << 9) | (bid >> 3);
  const int cg = 2 * cgp + w;
  const int c = cg >> 11;  // / G_

  for (int i = tid; i < 2 * S_ * L_; i += 128)  // strided: 192 > 128 threads
    sidx[i] = Idx[(size_t)(2 * cgp) * (S_ * L_) + i];
  const float mprev = slot_max(slots, prev_slot);
  const float scale = (mprev > 1.0f) ? (1.0f / mprev) : 1.0f;
  const float s3 = scale * scale * scale;
  const float K = s3 * INVG_LOG2E_;
  __syncthreads();

  const int* widx = sidx + w * (S_ * L_);
  const __half* Ac = A16 + (size_t)c * cstride;

  float M0 = -1.0f, M1 = -1.0f;  // body products are in [0,1]
  float acc0 = 0.0f, acc1 = 0.0f;
#pragma unroll
  for (int s0 = 0; s0 < S_; s0 += 8) {
    // 24 independent 256 B row-requests in flight
    __half2 v[24];
#pragma unroll
    for (int j = 0; j < 24; ++j) {
      const int row = __builtin_amdgcn_readfirstlane(widx[s0 * 3 + j]);
      v[j] =
          *reinterpret_cast<const __half2*>(Ac + (size_t)row * B_ + 2 * lane);
    }
    float b0[8], b1[8];
#pragma unroll
    for (int k = 0; k < 8; ++k) {
      const float2 f0 = __half22float2(v[3 * k + 0]);
      const float2 f1 = __half22float2(v[3 * k + 1]);
      const float2 f2 = __half22float2(v[3 * k + 2]);
      b0[k] = f0.x * f1.x * f2.x;
      b1[k] = f0.y * f1.y * f2.y;
    }
    float cm0 = b0[0], cm1 = b1[0];
#pragma unroll
    for (int k = 1; k < 8; ++k) {
      cm0 = fmaxf(cm0, b0[k]);
      cm1 = fmaxf(cm1, b1[k]);
    }
    const float Mn0 = fmaxf(M0, cm0);
    const float Mn1 = fmaxf(M1, cm1);
    acc0 *= exp2f((M0 - Mn0) * K);  // one rescale per chunk
    acc1 *= exp2f((M1 - Mn1) * K);
#pragma unroll
    for (int k = 0; k < 8; ++k) {
      acc0 += exp2f((b0[k] - Mn0) * K);
      acc1 += exp2f((b1[k] - Mn1) * K);
    }
    M0 = Mn0;
    M1 = Mn1;
  }
  const float lse0 = M0 * s3 + GAMMA_LN2_ * log2f(acc0);
  const float lse1 = M1 * s3 + GAMMA_LN2_ * log2f(acc1);
  *reinterpret_cast<float2*>(Lout + (size_t)cg * B_ + 2 * lane) =
      make_float2(lse0, lse1);

  // per-wave max -> one banked global atomic per wave
  float t = fmaxf(lse0, lse1);
#pragma unroll
  for (int off = 32; off >= 1; off >>= 1) t = fmaxf(t, __shfl_xor(t, off));
  if (lane == 0)
    atomicMax(slots + out_slot * SLOT_U_ + (bid & 7) * BANK_U_,
              __float_as_uint(t));
}

// ---------------------------------------------------------------------------
// k_elem: R = Rin*sprev; ce = lse1*s1; A = 2-elem softor(R, ce); also emits
// the fp16 mirror A16 for the next step's gather (skipped on the last step).
// Rin/rstride lets step 0 read the 1 MB xT (clause-stride 0).
// Exactly one float4 per thread: 1024 blocks x 256 threads x 4 = C*G*B.
// ---------------------------------------------------------------------------
__global__ __launch_bounds__(256) void k_elem(
    const float* __restrict__ Rin, size_t rstride, float* __restrict__ A,
    __half* __restrict__ A16, const float* __restrict__ Lin, uint32_t* slots,
    int prev_slot, int m1_slot, int out_slot) {
  __shared__ float wmax[4];
  const float mprev = slot_max(slots, prev_slot);
  const float sprev = (mprev > 1.0f) ? (1.0f / mprev) : 1.0f;
  const float m1 = slot_max(slots, m1_slot);
  const float s1 = (m1 > 1.0f) ? (1.0f / m1) : 1.0f;

  const int e = (blockIdx.x * 256 + threadIdx.x) * 4;
  const int c = e >> 18;              // / (G_*B_)
  const int rem = e & (G_ * B_ - 1);  // within clause slice
  const float4 Rv =
      *reinterpret_cast<const float4*>(Rin + (size_t)c * rstride + rem);
  const float4 Lv = *reinterpret_cast<const float4*>(Lin + e);

  float r[4] = {Rv.x, Rv.y, Rv.z, Rv.w};
  float l[4] = {Lv.x, Lv.y, Lv.z, Lv.w};
  float o[4];
  float tmax = 0.0f;
#pragma unroll
  for (int k = 0; k < 4; ++k) {
    const float R = r[k] * sprev;
    const float ce = l[k] * s1;
    const float M = fmaxf(R, ce);
    const float mn = fminf(R, ce);
    const float lse2 =
        M + GAMMA_LN2_ * log2f(1.0f + exp2f((mn - M) * INVG_LOG2E_));
    o[k] = lse2;
    tmax = fmaxf(tmax, lse2);
  }
  *reinterpret_cast<float4*>(A + e) = make_float4(o[0], o[1], o[2], o[3]);
  if (A16) {
    union {
      __half2 h[2];
      uint2 u;
    } pk;
    pk.h[0] = __floats2half2_rn(o[0], o[1]);
    pk.h[1] = __floats2half2_rn(o[2], o[3]);
    *reinterpret_cast<uint2*>(A16 + e) = pk.u;
  }

  float t = tmax;
#pragma unroll
  for (int off = 32; off >= 1; off >>= 1) t = fmaxf(t, __shfl_xor(t, off));
  if ((threadIdx.x & 63) == 0) wmax[threadIdx.x >> 6] = t;
  __syncthreads();
  if (threadIdx.x == 0) {
    const float bm = fmaxf(fmaxf(wmax[0], wmax[1]), fmaxf(wmax[2], wmax[3]));
    atomicMax(slots + out_slot * SLOT_U_ + (blockIdx.x & 7) * BANK_U_,
              __float_as_uint(bm));
  }
}

// ---------------------------------------------------------------------------
// k_out: out[c,b,g] = A[c,g,b] * final_scale  (LDS-tiled transpose back)
// ---------------------------------------------------------------------------
__global__ __launch_bounds__(256) void k_out(const float* __restrict__ A,
                                             float* __restrict__ out,
                                             const uint32_t* __restrict__ slots,
                                             int mslot) {
  __shared__ float tile[32][33];
  const float mfin = slot_max(slots, mslot);
  const float sc = (mfin > 1.0f) ? (1.0f / mfin) : 1.0f;
  const int g0 = blockIdx.x * 32, b0 = blockIdx.y * 32, c = blockIdx.z;
  const int tx = threadIdx.x;
  for (int j = threadIdx.y; j < 32; j += 8)
    tile[j][tx] = A[((size_t)c * G_ + g0 + j) * B_ + b0 + tx];  // tile[g][b]
  __syncthreads();
  for (int i = threadIdx.y; i < 32; i += 8)
    out[((size_t)c * B_ + b0 + i) * G_ + g0 + tx] = tile[tx][i] * sc;
}

extern "C" void kernel_launch(void* const* d_in, const int* in_sizes, int n_in,
                              void* d_out, int out_size, void* d_ws,
                              size_t ws_size, hipStream_t stream) {
  const float* x = (const float*)d_in[0];  // [B,G]
  const int* Idx = (const int*)d_in[1];    // [C,G,S,L]
  float* out = (float*)d_out;              // [C,B,G]

  const size_t CS = (size_t)G_ * B_;  // 262144 elems per clause slice
  char* ws = (char*)d_ws;
  uint32_t* slots = (uint32_t*)ws;          // 7 slots x 1 KB
  float* A = (float*)(ws + 16384);          // 4 MB fp32 valuations [c,g,b]
  float* Lb = A + CS * C_;                  // 4 MB gather lse output
  float* xT = Lb + CS * C_;                 // 1 MB fp32 x^T
  __half* A16 = (__half*)(xT + CS);         // 2 MB fp16 mirror of A
  __half* x16 = A16 + CS * C_;              // 0.5 MB fp16 mirror of xT

  hipMemsetAsync(slots, 0, 8192, stream);

  k_initT<<<dim3(G_ / 32, B_ / 32), dim3(32, 8), 0, stream>>>(x, xT, x16);

  for (int step = 0; step < NSTEP_; ++step) {
    const int prev = 2 * step;  // m2 of previous step (all-zero -> scale 1)
    const int m1s = 2 * step + 1;
    const int m2s = 2 * step + 2;
    const __half* Gsrc = (step == 0) ? x16 : A16;
    const size_t gs = (step == 0) ? 0 : CS;
    const float* Rsrc = (step == 0) ? xT : A;
    const size_t rs = (step == 0) ? 0 : CS;
    __half* A16out = (step < NSTEP_ - 1) ? A16 : nullptr;  // dead on last step
    k_gather<<<(C_ * G_) / 2, 128, 0, stream>>>(Gsrc, gs, Idx, Lb, slots, prev,
                                                m1s);
    k_elem<<<(C_ * G_ * B_) / (256 * 4), 256, 0, stream>>>(
        Rsrc, rs, A, A16out, Lb, slots, prev, m1s, m2s);
  }

  k_out<<<dim3(G_ / 32, B_ / 32, C_), dim3(32, 8), 0, stream>>>(A, out, slots,
                                                                2 * NSTEP_);
}

// Round 6
// 154.259 us; speedup vs baseline: 1.5811x; 1.0042x over previous
//
#include <hip/hip_runtime.h>
#include <hip/hip_fp16.h>
#include <cstdint>
#include <cstddef>

// Problem constants (from reference setup_inputs)
#define C_ 4
#define B_ 128
#define G_ 2048
#define S_ 32
#define L_ 3
#define NSTEP_ 3
#define GAMMA_ 0.01f
// exp((x)*100) == exp2((x)*144.2695...), gamma*ln(a) = gamma*ln2*log2(a)
#define INVG_LOG2E_ 144.26950408889634f
#define GAMMA_LN2_ 0.0069314718055994530942f

// Slot layout: slot s = 1 KB (256 uints) with 8 atomic banks at 128 B stride
// (one L2 line each) -> 8-way spread of same-slot atomicMax traffic.
#define SLOT_U_ 256
#define BANK_U_ 32
__device__ __forceinline__ float slot_max(const uint32_t* slots, int slot) {
  float m = 0.0f;
#pragma unroll
  for (int k = 0; k < 8; ++k)
    m = fmaxf(m, __uint_as_float(slots[slot * SLOT_U_ + k * BANK_U_]));
  return m;
}

// ---------------------------------------------------------------------------
// k_initT: xT[g,b] = x[b,g] (fp32, 1 MB) and x16[g,b] (fp16 mirror, 0.5 MB).
// Block (0,0) also zeroes the slot region (replaces the hipMemsetAsync
// dispatch; ordering vs gather is by stream order, not intra-kernel).
// ---------------------------------------------------------------------------
__global__ __launch_bounds__(256) void k_initT(const float* __restrict__ x,
                                               float* __restrict__ xT,
                                               __half* __restrict__ x16,
                                               uint32_t* __restrict__ slots) {
  if (blockIdx.x == 0 && blockIdx.y == 0) {
    const int t = threadIdx.y * 32 + threadIdx.x;
    for (int i = t; i < 2048; i += 256) slots[i] = 0u;  // 8 KB
  }
  __shared__ float tile[32][33];
  const int g0 = blockIdx.x * 32, b0 = blockIdx.y * 32;
  const int tx = threadIdx.x;
  for (int i = threadIdx.y; i < 32; i += 8)
    tile[i][tx] = x[(size_t)(b0 + i) * G_ + g0 + tx];  // tile[b-b0][g-g0]
  __syncthreads();
  for (int j = threadIdx.y; j < 32; j += 8) {
    const float v = tile[tx][j];
    xT[(size_t)(g0 + j) * B_ + b0 + tx] = v;
    x16[(size_t)(g0 + j) * B_ + b0 + tx] = __float2half_rn(v);
  }
}

// ---------------------------------------------------------------------------
// k_gather: ONE WAVE per (c,g); 64 lanes x __half2 = whole 128-b fp16 row in
// one 256 B request. 256-thr blocks = 4 waves = 4 cg; 2048 blocks.
// Indices are REGISTER-resident: one int4 vector load puts the wave's 96
// indices in lanes 0..23; each row index is extracted with readlane at
// compile-time (src lane = j/4, component = j%4) -> wave-uniform scalar,
// scalar address path, NO LDS, NO barriers, no ds_read latency in the
// load-address chain (round-5's bottleneck theory).
// Chunked online logsumexp (8 subs/chunk) bounds live registers.
// XCD-bijective swizzle keeps each XCD's L2 on one clause slice.
// ---------------------------------------------------------------------------
__global__ __launch_bounds__(256) void k_gather(
    const __half* __restrict__ A16, size_t cstride,
    const int* __restrict__ Idx, float* __restrict__ Lout,
    uint32_t* slots, int prev_slot, int out_slot) {
  const int tid = threadIdx.x;
  const int lane = tid & 63;
  const int w = tid >> 6;
  const int bid = blockIdx.x;
  // bijective: 8 xcd x 256 runs x 4 waves = 8192 cg; each XCD stays in
  // [xcd*1024, xcd*1024+1024) = half a clause slice.
  const int cg = ((bid & 7) << 10) | (((bid >> 3) << 2) | w);
  const int c = cg >> 11;  // / G_

  // wave's 96 indices in one 16B vector load (lanes 0..23)
  int4 idx4 = make_int4(0, 0, 0, 0);
  const int4* Ip = reinterpret_cast<const int4*>(Idx + (size_t)cg * (S_ * L_));
  if (lane < 24) idx4 = Ip[lane];

  const float mprev = slot_max(slots, prev_slot);
  const float scale = (mprev > 1.0f) ? (1.0f / mprev) : 1.0f;
  const float s3 = scale * scale * scale;
  const float K = s3 * INVG_LOG2E_;

  const __half* Ac = A16 + (size_t)c * cstride;

  float M0 = -1.0f, M1 = -1.0f;  // body products are in [0,1]
  float acc0 = 0.0f, acc1 = 0.0f;
#pragma unroll
  for (int s0 = 0; s0 < S_; s0 += 8) {
    // 24 independent 256 B row-requests; addresses from readlane scalars
    __half2 v[24];
#pragma unroll
    for (int j = 0; j < 24; ++j) {
      const int flat = s0 * 3 + j;  // compile-time
      const int src = flat >> 2;
      const int comp = flat & 3;
      int row;
      if (comp == 0)
        row = __builtin_amdgcn_readlane(idx4.x, src);
      else if (comp == 1)
        row = __builtin_amdgcn_readlane(idx4.y, src);
      else if (comp == 2)
        row = __builtin_amdgcn_readlane(idx4.z, src);
      else
        row = __builtin_amdgcn_readlane(idx4.w, src);
      v[j] =
          *reinterpret_cast<const __half2*>(Ac + (size_t)row * B_ + 2 * lane);
    }
    float b0[8], b1[8];
#pragma unroll
    for (int k = 0; k < 8; ++k) {
      const float2 f0 = __half22float2(v[3 * k + 0]);
      const float2 f1 = __half22float2(v[3 * k + 1]);
      const float2 f2 = __half22float2(v[3 * k + 2]);
      b0[k] = f0.x * f1.x * f2.x;
      b1[k] = f0.y * f1.y * f2.y;
    }
    float cm0 = b0[0], cm1 = b1[0];
#pragma unroll
    for (int k = 1; k < 8; ++k) {
      cm0 = fmaxf(cm0, b0[k]);
      cm1 = fmaxf(cm1, b1[k]);
    }
    const float Mn0 = fmaxf(M0, cm0);
    const float Mn1 = fmaxf(M1, cm1);
    acc0 *= exp2f((M0 - Mn0) * K);  // one rescale per chunk
    acc1 *= exp2f((M1 - Mn1) * K);
#pragma unroll
    for (int k = 0; k < 8; ++k) {
      acc0 += exp2f((b0[k] - Mn0) * K);
      acc1 += exp2f((b1[k] - Mn1) * K);
    }
    M0 = Mn0;
    M1 = Mn1;
  }
  const float lse0 = M0 * s3 + GAMMA_LN2_ * log2f(acc0);
  const float lse1 = M1 * s3 + GAMMA_LN2_ * log2f(acc1);
  *reinterpret_cast<float2*>(Lout + (size_t)cg * B_ + 2 * lane) =
      make_float2(lse0, lse1);

  // per-wave max -> one banked global atomic per wave
  float t = fmaxf(lse0, lse1);
#pragma unroll
  for (int off = 32; off >= 1; off >>= 1) t = fmaxf(t, __shfl_xor(t, off));
  if (lane == 0)
    atomicMax(slots + out_slot * SLOT_U_ + (bid & 7) * BANK_U_,
              __float_as_uint(t));
}

// ---------------------------------------------------------------------------
// k_elem: R = Rin*sprev; ce = lse1*s1; A = 2-elem softor(R, ce); also emits
// the fp16 mirror A16 for the next step's gather (skipped on the last step).
// Rin/rstride lets step 0 read the 1 MB xT (clause-stride 0).
// Exactly one float4 per thread: 1024 blocks x 256 threads x 4 = C*G*B.
// ---------------------------------------------------------------------------
__global__ __launch_bounds__(256) void k_elem(
    const float* __restrict__ Rin, size_t rstride, float* __restrict__ A,
    __half* __restrict__ A16, const float* __restrict__ Lin, uint32_t* slots,
    int prev_slot, int m1_slot, int out_slot) {
  __shared__ float wmax[4];
  const float mprev = slot_max(slots, prev_slot);
  const float sprev = (mprev > 1.0f) ? (1.0f / mprev) : 1.0f;
  const float m1 = slot_max(slots, m1_slot);
  const float s1 = (m1 > 1.0f) ? (1.0f / m1) : 1.0f;

  const int e = (blockIdx.x * 256 + threadIdx.x) * 4;
  const int c = e >> 18;              // / (G_*B_)
  const int rem = e & (G_ * B_ - 1);  // within clause slice
  const float4 Rv =
      *reinterpret_cast<const float4*>(Rin + (size_t)c * rstride + rem);
  const float4 Lv = *reinterpret_cast<const float4*>(Lin + e);

  float r[4] = {Rv.x, Rv.y, Rv.z, Rv.w};
  float l[4] = {Lv.x, Lv.y, Lv.z, Lv.w};
  float o[4];
  float tmax = 0.0f;
#pragma unroll
  for (int k = 0; k < 4; ++k) {
    const float R = r[k] * sprev;
    const float ce = l[k] * s1;
    const float M = fmaxf(R, ce);
    const float mn = fminf(R, ce);
    const float lse2 =
        M + GAMMA_LN2_ * log2f(1.0f + exp2f((mn - M) * INVG_LOG2E_));
    o[k] = lse2;
    tmax = fmaxf(tmax, lse2);
  }
  *reinterpret_cast<float4*>(A + e) = make_float4(o[0], o[1], o[2], o[3]);
  if (A16) {
    union {
      __half2 h[2];
      uint2 u;
    } pk;
    pk.h[0] = __floats2half2_rn(o[0], o[1]);
    pk.h[1] = __floats2half2_rn(o[2], o[3]);
    *reinterpret_cast<uint2*>(A16 + e) = pk.u;
  }

  float t = tmax;
#pragma unroll
  for (int off = 32; off >= 1; off >>= 1) t = fmaxf(t, __shfl_xor(t, off));
  if ((threadIdx.x & 63) == 0) wmax[threadIdx.x >> 6] = t;
  __syncthreads();
  if (threadIdx.x == 0) {
    const float bm = fmaxf(fmaxf(wmax[0], wmax[1]), fmaxf(wmax[2], wmax[3]));
    atomicMax(slots + out_slot * SLOT_U_ + (blockIdx.x & 7) * BANK_U_,
              __float_as_uint(bm));
  }
}

// ---------------------------------------------------------------------------
// k_out: out[c,b,g] = A[c,g,b] * final_scale  (LDS-tiled transpose back)
// ---------------------------------------------------------------------------
__global__ __launch_bounds__(256) void k_out(const float* __restrict__ A,
                                             float* __restrict__ out,
                                             const uint32_t* __restrict__ slots,
                                             int mslot) {
  __shared__ float tile[32][33];
  const float mfin = slot_max(slots, mslot);
  const float sc = (mfin > 1.0f) ? (1.0f / mfin) : 1.0f;
  const int g0 = blockIdx.x * 32, b0 = blockIdx.y * 32, c = blockIdx.z;
  const int tx = threadIdx.x;
  for (int j = threadIdx.y; j < 32; j += 8)
    tile[j][tx] = A[((size_t)c * G_ + g0 + j) * B_ + b0 + tx];  // tile[g][b]
  __syncthreads();
  for (int i = threadIdx.y; i < 32; i += 8)
    out[((size_t)c * B_ + b0 + i) * G_ + g0 + tx] = tile[tx][i] * sc;
}

extern "C" void kernel_launch(void* const* d_in, const int* in_sizes, int n_in,
                              void* d_out, int out_size, void* d_ws,
                              size_t ws_size, hipStream_t stream) {
  const float* x = (const float*)d_in[0];  // [B,G]
  const int* Idx = (const int*)d_in[1];    // [C,G,S,L]
  float* out = (float*)d_out;              // [C,B,G]

  const size_t CS = (size_t)G_ * B_;  // 262144 elems per clause slice
  char* ws = (char*)d_ws;
  uint32_t* slots = (uint32_t*)ws;          // 7 slots x 1 KB
  float* A = (float*)(ws + 16384);          // 4 MB fp32 valuations [c,g,b]
  float* Lb = A + CS * C_;                  // 4 MB gather lse output
  float* xT = Lb + CS * C_;                 // 1 MB fp32 x^T
  __half* A16 = (__half*)(xT + CS);         // 2 MB fp16 mirror of A
  __half* x16 = A16 + CS * C_;              // 0.5 MB fp16 mirror of xT

  k_initT<<<dim3(G_ / 32, B_ / 32), dim3(32, 8), 0, stream>>>(x, xT, x16,
                                                              slots);

  for (int step = 0; step < NSTEP_; ++step) {
    const int prev = 2 * step;  // m2 of previous step (all-zero -> scale 1)
    const int m1s = 2 * step + 1;
    const int m2s = 2 * step + 2;
    const __half* Gsrc = (step == 0) ? x16 : A16;
    const size_t gs = (step == 0) ? 0 : CS;
    const float* Rsrc = (step == 0) ? xT : A;
    const size_t rs = (step == 0) ? 0 : CS;
    __half* A16out = (step < NSTEP_ - 1) ? A16 : nullptr;  // dead on last step
    k_gather<<<(C_ * G_) / 4, 256, 0, stream>>>(Gsrc, gs, Idx, Lb, slots, prev,
                                                m1s);
    k_elem<<<(C_ * G_ * B_) / (256 * 4), 256, 0, stream>>>(
        Rsrc, rs, A, A16out, Lb, slots, prev, m1s, m2s);
  }

  k_out<<<dim3(G_ / 32, B_ / 32, C_), dim3(32, 8), 0, stream>>>(A, out, slots,
                                                                2 * NSTEP_);
}